// Round 18
// baseline (676.845 us; speedup 1.0000x reference)
//
#include <hip/hip_runtime.h>
#include <hip/hip_bf16.h>
#include <math.h>

// Problem constants
constexpr int kD  = 1024;
constexpr int kH1 = 4096;
constexpr int kO  = 1024;
constexpr int kE  = 8;
constexpr int kB  = 8192;

constexpr int BM   = 128;            // row-tile
constexpr int MAXT = kB / BM + kE;   // 72 row-tiles upper bound

typedef __attribute__((ext_vector_type(8))) short short8;
typedef __attribute__((ext_vector_type(4))) float f32x4;

__device__ __forceinline__ unsigned short f2bf(float f) {
  unsigned int u = __float_as_uint(f);
  u += 0x7fffu + ((u >> 16) & 1u);
  return (unsigned short)(u >> 16);
}

// tanh-form gelu (max |err| vs erf-gelu ~1e-3, << bf16 noise)
__device__ __forceinline__ float gelu_fast(float x) {
  float u = 0.7978845608028654f * (x + 0.044715f * x * x * x);
  float eu = __expf(2.0f * u);
  float th = 1.0f - 2.0f / (eu + 1.0f);
  return 0.5f * x * (1.0f + th);
}

__device__ __forceinline__ void cvt8(const float* __restrict__ src,
                                     unsigned short* __restrict__ dst) {
  const float4* s = (const float4*)src;
  float4 f0 = s[0], f1 = s[1];
  short8 v;
  v[0] = (short)f2bf(f0.x); v[1] = (short)f2bf(f0.y);
  v[2] = (short)f2bf(f0.z); v[3] = (short)f2bf(f0.w);
  v[4] = (short)f2bf(f1.x); v[5] = (short)f2bf(f1.y);
  v[6] = (short)f2bf(f1.z); v[7] = (short)f2bf(f1.w);
  *(short8*)dst = v;
}

// ---------------------------------------------------------------------------
// Setup: per-expert counts, permutation, 128-row tile table.
// ---------------------------------------------------------------------------
__global__ __launch_bounds__(256) void setup_kernel(const int* __restrict__ eid,
                                                    int* __restrict__ perm,
                                                    int* __restrict__ tiles) {
  __shared__ int cnt[kE];
  __shared__ int off[kE];
  __shared__ int cur[kE];
  int t = threadIdx.x;
  if (t < kE) { cnt[t] = 0; cur[t] = 0; }
  __syncthreads();
  for (int i = t; i < kB; i += 256) atomicAdd(&cnt[eid[i]], 1);
  __syncthreads();
  if (t == 0) {
    int o = 0, nt = 0;
    for (int e = 0; e < kE; ++e) {
      off[e] = o;
      int c = cnt[e];
      for (int r = 0; r < c; r += BM) {
        tiles[nt * 4 + 0] = e;
        tiles[nt * 4 + 1] = o + r;
        tiles[nt * 4 + 2] = (c - r < BM) ? (c - r) : BM;
        tiles[nt * 4 + 3] = 0;
        ++nt;
      }
      o += c;
    }
    for (; nt < MAXT; ++nt) {
      tiles[nt * 4 + 0] = 0; tiles[nt * 4 + 1] = 0;
      tiles[nt * 4 + 2] = 0; tiles[nt * 4 + 3] = 0;
    }
  }
  __syncthreads();
  for (int i = t; i < kB; i += 256) {
    int e = eid[i];
    int p = off[e] + atomicAdd(&cur[e], 1);
    perm[p] = i;
  }
}

// ---------------------------------------------------------------------------
// Prep: gather x->xg (blocks 0..4095) + convert W1->bf16 (blocks 4096..6143).
// Block-range split (R12 lesson: per-thread interleave kills DRAM eff).
// ---------------------------------------------------------------------------
constexpr int kGB = kB * kD / 8 / 256;    // 4096 gather blocks
constexpr int kCN = kE * kH1 * kD / 8;    // 4.19M convert vec8 units

__global__ __launch_bounds__(256) void prep_kernel(
    const float* __restrict__ x, const int* __restrict__ perm,
    unsigned short* __restrict__ xg,
    const float* __restrict__ W1, unsigned short* __restrict__ W1b) {
  const int b = blockIdx.x;
  if (b < kGB) {
    int idx = b * 256 + threadIdx.x;
    int pos = idx >> 7;
    int c   = (idx & 127) << 3;
    cvt8(x + (size_t)perm[pos] * kD + c, xg + (size_t)pos * kD + c);
  } else {
    const int cb = b - kGB;                 // 0..2047
    const int stride = 2048 * 256;
    for (int i = cb * 256 + threadIdx.x; i < kCN; i += stride)
      cvt8(W1 + (size_t)i * 8, W1b + (size_t)i * 8);
  }
}

__global__ __launch_bounds__(256) void convert_kernel(const float* __restrict__ src,
                                                      unsigned short* __restrict__ dst,
                                                      int n8) {
  int stride = gridDim.x * 256;
  for (int i = blockIdx.x * 256 + threadIdx.x; i < n8; i += stride)
    cvt8(src + (size_t)i * 8, dst + (size_t)i * 8);
}

// ---------------------------------------------------------------------------
// 128xBN BK=32 grouped GEMM, A-DIRECT: A fragments loaded from global
// (L2/L3-resident) straight to registers; only B staged in LDS.
// LDS = 3 bufs x (BN x 32 x 2B = BN*64 bytes); BN=256 -> 48KB, BN=128 -> 24KB.
// 8 waves: wave w rows (w>>2)*64, cols (w&3)*(BN/4).  Per kt:
//   {vmcnt(BISS) [drains B(kt); no-op steady]; barrier; loadA (4 global,
//    compiler-tracked -> its auto-wait is vmcnt(BISS), staging stays in
//    flight); readB (imm-offset ds_read_b128, swizzle g^((row>>1)&3),
//    proven 0-conflict); stageB(kt+2) LAST (newest); MFMA}.
// One barrier/kt: each wave's kt-1 ds_reads completed (lgkm before its
// MFMA) before it reaches kt's barrier -> stage overwrite race-free.
// MODE 0: gelu->bf16 out_bf perm-space.  MODE 1: fp32 +bias scatter.
// ---------------------------------------------------------------------------
template <int KTOT, int N, int NPAN, int BN, int MODE>
__global__ __launch_bounds__(512, 4) void gemmad_kernel(
    const unsigned short* __restrict__ Amat,
    const unsigned short* __restrict__ Bmat,
    const float* __restrict__ bias,
    const int* __restrict__ tiles,
    const int* __restrict__ perm,
    unsigned short* __restrict__ out_bf,
    float* __restrict__ out_f) {
  extern __shared__ char lds[];            // 3 x (BN*64)
  constexpr int NKt  = KTOT / 32;
  constexpr int BISS = BN / 128;           // staging issues per kt
  constexpr int NC   = BN / 64;            // b-frag cols per wave (16-wide)
  constexpr int BUFB = BN * 64;            // bytes per B buffer
  constexpr int TOTAL = MAXT * NPAN;
  constexpr int cpx = TOTAL / 8;
  constexpr int nchN = (NPAN >= 4) ? NPAN / 4 : 1;

  const int bid = blockIdx.x;
  const int id = (bid & 7) * cpx + (bid >> 3);
  const int chunk = id >> 4, a16 = id & 15;
  const int ti = (chunk / nchN) * 4 + (a16 & 3);
  const int pancol = (chunk % nchN) * 4 + (a16 >> 2);
  const int n0 = pancol * BN;

  const int e  = tiles[ti * 4 + 0];
  const int rs = tiles[ti * 4 + 1];
  const int nr = tiles[ti * 4 + 2];
  if (nr == 0) return;

  const int t = threadIdx.x;
  const int l = t & 63;
  const int w = t >> 6;
  const int lr = l & 15, g = l >> 4;
  const int wr = w >> 2;      // 0..1
  const int wc = w & 3;       // 0..3

  const unsigned short* Bp = Bmat + (size_t)e * N * KTOT;

  // ---- A-direct per-mr global base pointers (fragment: row=lr, k=g*8) ----
  const unsigned short* A0 = Amat + (size_t)(rs + wr * 64 + 0 * 16 + lr) * KTOT + g * 8;
  const unsigned short* A1 = Amat + (size_t)(rs + wr * 64 + 1 * 16 + lr) * KTOT + g * 8;
  const unsigned short* A2 = Amat + (size_t)(rs + wr * 64 + 2 * 16 + lr) * KTOT + g * 8;
  const unsigned short* A3 = Amat + (size_t)(rs + wr * 64 + 3 * 16 + lr) * KTOT + g * 8;

  // ---- B staging source (per-thread constants) ----
  const int sR = t >> 2;                       // 0..127
  const int sG = (t & 3) ^ ((sR >> 1) & 3);    // logical k-slot at phys t&3
  const unsigned short* BrowS0 = Bp + (size_t)(n0 + sR) * KTOT + sG * 8;
  const unsigned short* BrowS1 = Bp + (size_t)(n0 + 128 + sR) * KTOT + sG * 8;

  auto stageB = [&](char* buf, int k0) {
    __builtin_amdgcn_global_load_lds(
        (const __attribute__((address_space(1))) unsigned int*)(BrowS0 + k0),
        (__attribute__((address_space(3))) unsigned int*)(buf + t * 16), 16, 0, 0);
    if constexpr (BISS == 2)
      __builtin_amdgcn_global_load_lds(
          (const __attribute__((address_space(1))) unsigned int*)(BrowS1 + k0),
          (__attribute__((address_space(3))) unsigned int*)(buf + 8192 + t * 16),
          16, 0, 0);
  };

  // ---- B read base (imm-offset; swizzle invariant across nc) ----
  const int rB0 = wc * (BN / 4) + lr;
  const int offB0 = rB0 * 64 + ((g ^ ((rB0 >> 1) & 3)) * 16);

  short8 aF[4], bF[NC];
  f32x4 acc[NC][4] = {};   // [nc][mr]

  auto mfmaAll = [&]() {
    __builtin_amdgcn_s_setprio(1);
#pragma unroll
    for (int nc = 0; nc < NC; ++nc)
#pragma unroll
      for (int mr = 0; mr < 4; ++mr)
        acc[nc][mr] = __builtin_amdgcn_mfma_f32_16x16x32_bf16(
            aF[mr], bF[nc], acc[nc][mr], 0, 0, 0);
    __builtin_amdgcn_s_setprio(0);
  };

  char* b0 = lds;
  char* b1 = lds + BUFB;
  char* b2 = lds + 2 * BUFB;

  // Prologue: stage B(kt0) -> b0, B(kt1) -> b1.
  stageB(b0, 0);
  stageB(b1, 32);

#pragma unroll 1
  for (int kt = 0; kt < NKt; ++kt) {
    // Drain B(kt) (issued 2 kts ago).  Steady-state no-op: compiler's A-wait
    // at kt-1 (vmcnt(BISS)) already drained it.
    if constexpr (BISS == 2) asm volatile("s_waitcnt vmcnt(2)" ::: "memory");
    else                     asm volatile("s_waitcnt vmcnt(1)" ::: "memory");
    __builtin_amdgcn_s_barrier();
    const int k0 = kt * 32;
    // A fragments: global -> regs (compiler tracks + waits vmcnt(BISS))
    aF[0] = *(const short8*)(A0 + k0);
    aF[1] = *(const short8*)(A1 + k0);
    aF[2] = *(const short8*)(A2 + k0);
    aF[3] = *(const short8*)(A3 + k0);
    // B fragments from LDS
#pragma unroll
    for (int nc = 0; nc < NC; ++nc)
      bF[nc] = *(const short8*)(b0 + offB0 + nc * 1024);
    // Stage kt+2 LAST (stays in flight across A-wait)
    if (kt + 2 < NKt) stageB(b2, (kt + 2) * 32);
    mfmaAll();
    // rotate ring
    char* tmp = b0; b0 = b1; b1 = b2; b2 = tmp;
  }

  // Epilogue.  D frag: row = wr*64 + mr*16 + (l>>4)*4 + rg;
  //            col = wc*(BN/4) + nc*16 + (l&15).
  const int lr4 = g * 4;
#pragma unroll
  for (int mr = 0; mr < 4; ++mr)
#pragma unroll
    for (int rg = 0; rg < 4; ++rg) {
      int row = wr * 64 + mr * 16 + lr4 + rg;
      if (row < nr) {
        if constexpr (MODE == 0) {
          unsigned short* dst = out_bf + (size_t)(rs + row) * N + n0 + wc * (BN / 4);
#pragma unroll
          for (int nc = 0; nc < NC; ++nc)
            dst[nc * 16 + lr] = f2bf(gelu_fast(acc[nc][mr][rg]));
        } else {
          int orig = perm[rs + row];
          float* dst = out_f + (size_t)orig * N + n0 + wc * (BN / 4);
          const float* bp = bias + (size_t)e * N + n0 + wc * (BN / 4);
#pragma unroll
          for (int nc = 0; nc < NC; ++nc)
            dst[nc * 16 + lr] = acc[nc][mr][rg] + bp[nc * 16 + lr];
        }
      }
    }
}

// ---------------------------------------------------------------------------
extern "C" void kernel_launch(void* const* d_in, const int* in_sizes, int n_in,
                              void* d_out, int out_size, void* d_ws, size_t ws_size,
                              hipStream_t stream) {
  const float* x  = (const float*)d_in[0];
  const int*  eid = (const int*)d_in[1];
  const float* W1 = (const float*)d_in[2];
  const float* W2 = (const float*)d_in[3];
  const float* b2 = (const float*)d_in[4];
  float* y = (float*)d_out;

  char* ws = (char*)d_ws;
  int* perm  = (int*)ws;                                   // 32KB
  int* tiles = (int*)(ws + 32768);                         // 4KB
  unsigned short* xg = (unsigned short*)(ws + 36864);      // [kB+128][kD]
  size_t xg_bytes = (size_t)(kB + 128) * kD * 2;           // 17,039,360
  unsigned short* h  = (unsigned short*)(ws + 36864 + xg_bytes);  // [kB+128][kH1]
  size_t h_bytes = (size_t)(kB + 128) * kH1 * 2;           // 68,157,440
  size_t w1b_off = 36864 + xg_bytes + h_bytes;
  unsigned short* W1b = (unsigned short*)(ws + w1b_off);   // 64MB
  size_t w2b_off = w1b_off + 67108864;
  const bool twobuf = ws_size >= w2b_off + 67108864;
  unsigned short* W2b = twobuf ? (unsigned short*)(ws + w2b_off) : W1b;

  auto g1 = gemmad_kernel<kD, kH1, 16, 256, 0>;   // 1152 blocks, 48KB LDS
  auto g2 = gemmad_kernel<kH1, kO, 8, 128, 1>;    // 576 blocks, 24KB LDS
  (void)hipFuncSetAttribute((const void*)g1, hipFuncAttributeMaxDynamicSharedMemorySize, 49152);
  (void)hipFuncSetAttribute((const void*)g2, hipFuncAttributeMaxDynamicSharedMemorySize, 24576);

  setup_kernel<<<1, 256, 0, stream>>>(eid, perm, tiles);

  // gather + W1 convert (block-range fused, both streaming)
  prep_kernel<<<kGB + 2048, 256, 0, stream>>>(x, perm, xg, W1, W1b);

  // GEMM1: h = gelu(xg @ W1[e]^T)
  g1<<<MAXT * 16, 512, 49152, stream>>>(xg, W1b, nullptr, tiles, perm, h, nullptr);

  // W2 -> bf16 (L3-warm for g2)
  convert_kernel<<<2048, 256, 0, stream>>>(W2, W2b, kCN);

  // GEMM2: y[orig] = h @ W2[e]^T + b2[e]  (full K, direct bias, no reduce)
  g2<<<MAXT * 8, 512, 24576, stream>>>(h, W2b, b2, tiles, perm, nullptr, y);
}

// Round 19
// 300.445 us; speedup vs baseline: 2.2528x; 2.2528x over previous
//
#include <hip/hip_runtime.h>
#include <hip/hip_bf16.h>
#include <math.h>

// Problem constants
constexpr int kD  = 1024;
constexpr int kH1 = 4096;
constexpr int kO  = 1024;
constexpr int kE  = 8;
constexpr int kB  = 8192;

constexpr int BM   = 128;            // row-tile
constexpr int MAXT = kB / BM + kE;   // 72 row-tiles upper bound

typedef __attribute__((ext_vector_type(8))) short short8;
typedef __attribute__((ext_vector_type(4))) float f32x4;

__device__ __forceinline__ unsigned short f2bf(float f) {
  unsigned int u = __float_as_uint(f);
  u += 0x7fffu + ((u >> 16) & 1u);
  return (unsigned short)(u >> 16);
}

// tanh-form gelu (max |err| vs erf-gelu ~1e-3, << bf16 noise)
__device__ __forceinline__ float gelu_fast(float x) {
  float u = 0.7978845608028654f * (x + 0.044715f * x * x * x);
  float eu = __expf(2.0f * u);
  float th = 1.0f - 2.0f / (eu + 1.0f);
  return 0.5f * x * (1.0f + th);
}

__device__ __forceinline__ void cvt8(const float* __restrict__ src,
                                     unsigned short* __restrict__ dst) {
  const float4* s = (const float4*)src;
  float4 f0 = s[0], f1 = s[1];
  short8 v;
  v[0] = (short)f2bf(f0.x); v[1] = (short)f2bf(f0.y);
  v[2] = (short)f2bf(f0.z); v[3] = (short)f2bf(f0.w);
  v[4] = (short)f2bf(f1.x); v[5] = (short)f2bf(f1.y);
  v[6] = (short)f2bf(f1.z); v[7] = (short)f2bf(f1.w);
  *(short8*)dst = v;
}

// ---------------------------------------------------------------------------
// Setup: per-expert counts, permutation, 128-row tile table.
// ---------------------------------------------------------------------------
__global__ __launch_bounds__(256) void setup_kernel(const int* __restrict__ eid,
                                                    int* __restrict__ perm,
                                                    int* __restrict__ tiles) {
  __shared__ int cnt[kE];
  __shared__ int off[kE];
  __shared__ int cur[kE];
  int t = threadIdx.x;
  if (t < kE) { cnt[t] = 0; cur[t] = 0; }
  __syncthreads();
  for (int i = t; i < kB; i += 256) atomicAdd(&cnt[eid[i]], 1);
  __syncthreads();
  if (t == 0) {
    int o = 0, nt = 0;
    for (int e = 0; e < kE; ++e) {
      off[e] = o;
      int c = cnt[e];
      for (int r = 0; r < c; r += BM) {
        tiles[nt * 4 + 0] = e;
        tiles[nt * 4 + 1] = o + r;
        tiles[nt * 4 + 2] = (c - r < BM) ? (c - r) : BM;
        tiles[nt * 4 + 3] = 0;
        ++nt;
      }
      o += c;
    }
    for (; nt < MAXT; ++nt) {
      tiles[nt * 4 + 0] = 0; tiles[nt * 4 + 1] = 0;
      tiles[nt * 4 + 2] = 0; tiles[nt * 4 + 3] = 0;
    }
  }
  __syncthreads();
  for (int i = t; i < kB; i += 256) {
    int e = eid[i];
    int p = off[e] + atomicAdd(&cur[e], 1);
    perm[p] = i;
  }
}

// ---------------------------------------------------------------------------
// Prep: gather x->xg (blocks 0..4095) + convert W1->bf16 (blocks 4096..6143).
// Block-range split (R12 lesson: per-thread interleave kills DRAM eff).
// ---------------------------------------------------------------------------
constexpr int kGB = kB * kD / 8 / 256;    // 4096 gather blocks
constexpr int kCN = kE * kH1 * kD / 8;    // 4.19M convert vec8 units

__global__ __launch_bounds__(256) void prep_kernel(
    const float* __restrict__ x, const int* __restrict__ perm,
    unsigned short* __restrict__ xg,
    const float* __restrict__ W1, unsigned short* __restrict__ W1b) {
  const int b = blockIdx.x;
  if (b < kGB) {
    int idx = b * 256 + threadIdx.x;
    int pos = idx >> 7;
    int c   = (idx & 127) << 3;
    cvt8(x + (size_t)perm[pos] * kD + c, xg + (size_t)pos * kD + c);
  } else {
    const int cb = b - kGB;                 // 0..2047
    const int stride = 2048 * 256;
    for (int i = cb * 256 + threadIdx.x; i < kCN; i += stride)
      cvt8(W1 + (size_t)i * 8, W1b + (size_t)i * 8);
  }
}

__global__ __launch_bounds__(256) void convert_kernel(const float* __restrict__ src,
                                                      unsigned short* __restrict__ dst,
                                                      int n8) {
  int stride = gridDim.x * 256;
  for (int i = blockIdx.x * 256 + threadIdx.x; i < n8; i += stride)
    cvt8(src + (size_t)i * 8, dst + (size_t)i * 8);
}

// ---------------------------------------------------------------------------
// 128x256 BK=32 grouped GEMM (R13-proven core: 112 us, 0 conflicts,
// 2 blocks/CU).  CONVW2: 512 TAIL blocks (bid >= MAXT*16) convert W2
// fp32->bf16 — appended after all GEMM blocks so they backfill CUs during
// g1's drain tail instead of displacing GEMM blocks at startup (R14's
// head-placement achieved zero overlap).  Complete before g2 by stream
// order.  GEMM path uses bid unmodified.
// MODE 0: gelu->bf16 out_bf perm-space.  MODE 1: fp32 +bias scatter.
// ---------------------------------------------------------------------------
template <int KTOT, int N, int NPAN, int MODE, int CONVW2>
__global__ __launch_bounds__(512, 2) void gemm32_kernel(
    const unsigned short* __restrict__ Amat,
    const unsigned short* __restrict__ Bmat,
    const float* __restrict__ bias,
    const int* __restrict__ tiles,
    const int* __restrict__ perm,
    unsigned short* __restrict__ out_bf,
    float* __restrict__ out_f,
    const float* __restrict__ csrc,
    unsigned short* __restrict__ cdst) {
  extern __shared__ char lds[];            // 3 x 24576
  constexpr int NKt = KTOT / 32;
  constexpr int TOTAL = MAXT * NPAN;
  constexpr int cpx = TOTAL / 8;
  constexpr int nchN = (NPAN >= 4) ? NPAN / 4 : 1;

  const int bid = blockIdx.x;
  const int t = threadIdx.x;

  if constexpr (CONVW2 > 0) {
    if (bid >= TOTAL) {
      // Tail converter: contiguous 1/512 chunk of W2 (8192 vec8 units).
      const int cb = bid - TOTAL;            // 0..511
      constexpr int per = kCN / 512;
      size_t u0 = (size_t)cb * per;
      for (int i = t; i < per; i += 512)
        cvt8(csrc + (u0 + i) * 8, cdst + (u0 + i) * 8);
      return;
    }
  }

  const int id = (bid & 7) * cpx + (bid >> 3);
  const int chunk = id >> 4, a16 = id & 15;
  const int ti = (chunk / nchN) * 4 + (a16 & 3);
  const int n0 = ((chunk % nchN) * 4 + (a16 >> 2)) * 256;

  const int e  = tiles[ti * 4 + 0];
  const int rs = tiles[ti * 4 + 1];
  const int nr = tiles[ti * 4 + 2];
  if (nr == 0) return;

  const int l = t & 63;
  const int w = t >> 6;
  const int lr = l & 15, g = l >> 4;
  const int wr = w >> 2;      // 0..1
  const int wc = w & 3;       // 0..3

  const unsigned short* Bp = Bmat + (size_t)e * N * KTOT;

  // ---- staging source (per-thread constants) ----
  const int sR = t >> 2;                       // 0..127
  const int sG = (t & 3) ^ ((sR >> 1) & 3);    // logical k-slot at phys t&3
  const unsigned short* ArowS = Amat + (size_t)(rs + sR) * KTOT + sG * 8;
  const unsigned short* BrowS0 = Bp + (size_t)(n0 + sR) * KTOT + sG * 8;
  const unsigned short* BrowS1 = Bp + (size_t)(n0 + 128 + sR) * KTOT + sG * 8;

  auto stageA = [&](char* buf, int k0) {
    __builtin_amdgcn_global_load_lds(
        (const __attribute__((address_space(1))) unsigned int*)(ArowS + k0),
        (__attribute__((address_space(3))) unsigned int*)(buf + t * 16), 16, 0, 0);
  };
  auto stageB = [&](char* buf, int k0, int i) {
    const unsigned short* src = (i ? BrowS1 : BrowS0) + k0;
    __builtin_amdgcn_global_load_lds(
        (const __attribute__((address_space(1))) unsigned int*)src,
        (__attribute__((address_space(3))) unsigned int*)(buf + 8192 + i * 8192 + t * 16),
        16, 0, 0);
  };

  // ---- read bases (imm-offset reads) ----
  const int rA = wr * 64 + lr;
  const int rB = wc * 64 + lr;
  const int offA0 = rA * 64 + ((g ^ ((rA >> 1) & 3)) * 16);
  const int offB0 = 8192 + rB * 64 + ((g ^ ((rB >> 1) & 3)) * 16);

  short8 aF[4], bF[4];
  f32x4 acc[4][4] = {};   // [nc][mr]

  auto readA = [&](char* buf) {
#pragma unroll
    for (int mr = 0; mr < 4; ++mr)
      aF[mr] = *(const short8*)(buf + offA0 + mr * 1024);
  };
  auto readB2 = [&](char* buf, int nclo) {
#pragma unroll
    for (int j = 0; j < 2; ++j)
      bF[nclo + j] = *(const short8*)(buf + offB0 + (nclo + j) * 1024);
  };
  auto mfmaH = [&](int nclo) {
    __builtin_amdgcn_s_setprio(1);
#pragma unroll
    for (int j = 0; j < 2; ++j)
#pragma unroll
      for (int mr = 0; mr < 4; ++mr)
        acc[nclo + j][mr] = __builtin_amdgcn_mfma_f32_16x16x32_bf16(
            aF[mr], bF[nclo + j], acc[nclo + j][mr], 0, 0, 0);
    __builtin_amdgcn_s_setprio(0);
  };

  char* b0 = lds;
  char* b1 = lds + 24576;
  char* b2 = lds + 49152;

  // Prologue: stage kt0 into b0, kt1 into b1.
  stageA(b0, 0);  stageB(b0, 0, 0);  stageB(b0, 0, 1);
  stageA(b1, 32); stageB(b1, 32, 0); stageB(b1, 32, 1);

#pragma unroll 1
  for (int kt = 0; kt < NKt; ++kt) {
    const int k0n = (kt + 2) * 32;
    const bool more = (kt + 2 < NKt);
    // Single counted wait: retires exactly this kt's 3 issues.
    if (kt == NKt - 1) asm volatile("s_waitcnt vmcnt(0)" ::: "memory");
    else               asm volatile("s_waitcnt vmcnt(3)" ::: "memory");
    __builtin_amdgcn_s_barrier();
    readA(b0);
    readB2(b0, 0);
    if (more) stageA(b2, k0n);
    __builtin_amdgcn_s_barrier();
    mfmaH(0);
    __builtin_amdgcn_s_barrier();
    readB2(b0, 2);
    if (more) { stageB(b2, k0n, 0); stageB(b2, k0n, 1); }
    __builtin_amdgcn_s_barrier();
    mfmaH(2);
    // rotate ring
    char* tmp = b0; b0 = b1; b1 = b2; b2 = tmp;
  }

  // Epilogue.  D frag: row = wr*64 + mr*16 + (l>>4)*4 + rg;
  //            col = wc*64 + nc*16 + (l&15).
  const int lr4 = g * 4;
#pragma unroll
  for (int mr = 0; mr < 4; ++mr)
#pragma unroll
    for (int rg = 0; rg < 4; ++rg) {
      int row = wr * 64 + mr * 16 + lr4 + rg;
      if (row < nr) {
        if constexpr (MODE == 0) {
          unsigned short* dst = out_bf + (size_t)(rs + row) * N + n0 + wc * 64;
#pragma unroll
          for (int nc = 0; nc < 4; ++nc)
            dst[nc * 16 + lr] = f2bf(gelu_fast(acc[nc][mr][rg]));
        } else {
          int orig = perm[rs + row];
          float* dst = out_f + (size_t)orig * N + n0 + wc * 64;
          const float* bp = bias + (size_t)e * N + n0 + wc * 64;
#pragma unroll
          for (int nc = 0; nc < 4; ++nc)
            dst[nc * 16 + lr] = acc[nc][mr][rg] + bp[nc * 16 + lr];
        }
      }
    }
}

// ---------------------------------------------------------------------------
extern "C" void kernel_launch(void* const* d_in, const int* in_sizes, int n_in,
                              void* d_out, int out_size, void* d_ws, size_t ws_size,
                              hipStream_t stream) {
  const float* x  = (const float*)d_in[0];
  const int*  eid = (const int*)d_in[1];
  const float* W1 = (const float*)d_in[2];
  const float* W2 = (const float*)d_in[3];
  const float* b2 = (const float*)d_in[4];
  float* y = (float*)d_out;

  char* ws = (char*)d_ws;
  int* perm  = (int*)ws;                                   // 32KB
  int* tiles = (int*)(ws + 32768);                         // 4KB
  unsigned short* xg = (unsigned short*)(ws + 36864);      // [kB+128][kD]
  size_t xg_bytes = (size_t)(kB + 128) * kD * 2;           // 17,039,360
  unsigned short* h  = (unsigned short*)(ws + 36864 + xg_bytes);  // [kB+128][kH1]
  size_t h_bytes = (size_t)(kB + 128) * kH1 * 2;           // 68,157,440
  size_t w1b_off = 36864 + xg_bytes + h_bytes;
  unsigned short* W1b = (unsigned short*)(ws + w1b_off);   // 64MB
  size_t w2b_off = w1b_off + 67108864;
  const bool twobuf = ws_size >= w2b_off + 67108864;
  unsigned short* W2b = twobuf ? (unsigned short*)(ws + w2b_off) : W1b;

  auto g1f = gemm32_kernel<kD, kH1, 16, 0, 1>;   // with W2-convert TAIL blocks
  auto g1s = gemm32_kernel<kD, kH1, 16, 0, 0>;
  auto g2  = gemm32_kernel<kH1, kO, 4, 1, 0>;
  (void)hipFuncSetAttribute((const void*)g1f, hipFuncAttributeMaxDynamicSharedMemorySize, 73728);
  (void)hipFuncSetAttribute((const void*)g1s, hipFuncAttributeMaxDynamicSharedMemorySize, 73728);
  (void)hipFuncSetAttribute((const void*)g2,  hipFuncAttributeMaxDynamicSharedMemorySize, 73728);

  setup_kernel<<<1, 256, 0, stream>>>(eid, perm, tiles);

  // gather + W1 convert (block-range fused, both streaming)
  prep_kernel<<<kGB + 2048, 256, 0, stream>>>(x, perm, xg, W1, W1b);

  if (twobuf) {
    // GEMM1 with 512 trailing W2-converter blocks (backfill drain slack)
    g1f<<<MAXT * 16 + 512, 512, 73728, stream>>>(
        xg, W1b, nullptr, tiles, perm, h, nullptr, W2, W2b);
  } else {
    g1s<<<MAXT * 16, 512, 73728, stream>>>(
        xg, W1b, nullptr, tiles, perm, h, nullptr, nullptr, nullptr);
    convert_kernel<<<2048, 256, 0, stream>>>(W2, W2b, kCN);
  }

  // GEMM2: y[orig] = h @ W2[e]^T + b2[e]  (full K, direct bias)
  g2<<<MAXT * 4, 512, 73728, stream>>>(
      h, W2b, b2, tiles, perm, nullptr, y, nullptr, nullptr);
}